// Round 6
// baseline (385.302 us; speedup 1.0000x reference)
//
#include <hip/hip_runtime.h>

// ---------------------------------------------------------------------------
// Refine_moduleGNN: dense strided conv + pre-MLP + 2x EdgeConv + head (MFMA).
// R1-R2: transpose+gather conv (150us conv path). R3: 265us total.
// R4/R5: sort (-) and fusion (-) both regressed -- reverted.
// R6: DENSE even-grid conv straight from fp32 CHW (no transpose/pad/sort):
//     gathered positions are always even coords -> 66x66x64 per batch.
//     352 blocks stream the image once, coalesced; scatter kernel builds
//     local[] from the L2-resident dense output (+bias, roi, graph fold-in).
// ---------------------------------------------------------------------------

typedef __bf16 bf16_t;
typedef bf16_t bf16x4 __attribute__((ext_vector_type(4)));
typedef bf16_t bf16x8 __attribute__((ext_vector_type(8)));
typedef float  f32x4  __attribute__((ext_vector_type(4)));

static constexpr int BATCH = 16;
static constexpr int NPT   = 512;
static constexpr int PTS   = BATCH * NPT;   // 8192

// dense conv output grid: 66 even yo x 68 xslots (66 valid) x 64 ch
static constexpr int YO = 66, XS = 68, OC = 64;

// ---- workspace layout (bytes) ----
static constexpr size_t OFF_WCONVP = 0;                                  // [64][16][256]
static constexpr size_t OFF_WPRE1  = OFF_WCONVP + (size_t)64*4096*2;     // [256][320]
static constexpr size_t OFF_WPRE2  = OFF_WPRE1  + (size_t)256*320*2;     // [256][256]
static constexpr size_t OFF_WEC1   = OFF_WPRE2  + (size_t)256*256*2;     // [512][256]
static constexpr size_t OFF_WEC2   = OFF_WEC1   + (size_t)512*256*2;
static constexpr size_t OFF_WQ1    = OFF_WEC2   + (size_t)512*256*2;     // [256][256]
static constexpr size_t OFF_WQ2    = OFF_WQ1    + (size_t)256*256*2;     // [64][256]
static constexpr size_t OFF_LOCAL  = OFF_WQ2    + (size_t)64*256*2;      // [8192][320] bf16
static constexpr size_t OFF_X      = OFF_LOCAL  + (size_t)PTS*320*2;
static constexpr size_t OFF_Y      = OFF_X      + (size_t)PTS*256*2;
static constexpr size_t OFF_Z      = OFF_Y      + (size_t)PTS*256*2;     // [8192][64]
// union: AB f32 (edgeconv) | Oconv bf16 (dense conv out, used before AB)
static constexpr size_t OFF_UNION  = OFF_Z      + (size_t)PTS*64*2;
static constexpr size_t AB_BYTES   = (size_t)PTS*512*4;                  // 16 MB
static constexpr size_t WS_NEEDED  = OFF_UNION + AB_BYTES;               // ~33.5 MB

// ---------------------------------------------------------------------------
// Weight prep: fp32 -> bf16, transposed layouts.
// ---------------------------------------------------------------------------
static constexpr int WP_CONVP = 64*4096;
static constexpr int WP_PRE1 = 256*320;
static constexpr int WP_PRE2 = 256*256;
static constexpr int WP_EC   = 512*256;
static constexpr int WP_Q1   = 256*256;
static constexpr int WP_Q2   = 64*256;
static constexpr int WP_TOTAL = WP_CONVP + WP_PRE1 + WP_PRE2 + 2*WP_EC + WP_Q1 + WP_Q2;

__global__ __launch_bounds__(256) void wprep_kernel(
    const float* __restrict__ conv_w, const float* __restrict__ pre_w1,
    const float* __restrict__ pre_w2, const float* __restrict__ g1_w,
    const float* __restrict__ g2_w,   const float* __restrict__ q_w1,
    const float* __restrict__ q_w2,
    bf16_t* __restrict__ wt_convp, bf16_t* __restrict__ wt_pre1,
    bf16_t* __restrict__ wt_pre2,  bf16_t* __restrict__ wt_ec1,
    bf16_t* __restrict__ wt_ec2,   bf16_t* __restrict__ wt_q1,
    bf16_t* __restrict__ wt_q2)
{
    int i = blockIdx.x * 256 + threadIdx.x;
    if (i >= WP_TOTAL) return;
    if (i < WP_CONVP) {   // [o][pix][c] <- conv_w[(o*256+c)*16 + pix]
        const int o = i >> 12, pix = (i >> 8) & 15, c = i & 255;
        wt_convp[i] = (bf16_t)conv_w[((o * 256 + c) << 4) + pix]; return; }
    i -= WP_CONVP;
    if (i < WP_PRE1) { int n = i / 320, k = i - n * 320;
        wt_pre1[i] = (bf16_t)pre_w1[k * 256 + n]; return; }
    i -= WP_PRE1;
    if (i < WP_PRE2) { int n = i >> 8, k = i & 255;
        wt_pre2[i] = (bf16_t)pre_w2[k * 256 + n]; return; }
    i -= WP_PRE2;
    if (i < WP_EC) { int n = i >> 8, k = i & 255;
        wt_ec1[i] = (bf16_t)(n < 256 ? g1_w[n * 512 + k] : g1_w[(n - 256) * 512 + 256 + k]);
        return; }
    i -= WP_EC;
    if (i < WP_EC) { int n = i >> 8, k = i & 255;
        wt_ec2[i] = (bf16_t)(n < 256 ? g2_w[n * 512 + k] : g2_w[(n - 256) * 512 + 256 + k]);
        return; }
    i -= WP_EC;
    if (i < WP_Q1) { int n = i >> 8, k = i & 255;
        wt_q1[i] = (bf16_t)q_w1[k * 256 + n]; return; }
    i -= WP_Q1;
    { int n = i >> 8, k = i & 255;
        wt_q2[i] = (bf16_t)q_w2[k * 64 + n]; }
}

// ---------------------------------------------------------------------------
// Dense strided conv: Oconv[b][yo][xs][o] for yo=2*yi (yi<66), xo=2*xs.
// Block = (b, ty) with ty<22 covering 3 even yo. Streams fp32 CHW once.
// K-chunks of 8 channels; LDS A: 8 rows x 139 px x (8ch pad 12) bf16.
// K order within chunk: 16 taps x 8 ch; MFMA kstep s: taps 4s..4s+3,
// lane khalf -> kx = khalf, ky = s (uniform) -> zero per-read addr math.
// ---------------------------------------------------------------------------
static constexpr int PXS = 139;           // px slot = x + 4, x in [-4,134]
static constexpr int CHP = 12;            // ch pad (8 used)
static constexpr int AROW = PXS * CHP;    // 1668 el
static constexpr int BROW = 152;          // 128 el used + pad

__global__ __launch_bounds__(256) void conv_dense(
    const float* __restrict__ img,        // [16][256][128][128]
    const bf16_t* __restrict__ Wc,        // [64][16][256] (o, pix, c)
    bf16_t* __restrict__ Oconv)           // [16][66][68][64]
{
    __shared__ bf16_t As[8 * AROW];       // 26.7 KB
    __shared__ bf16_t Bs[64 * BROW];      // 19.5 KB
    const int tid = threadIdx.x, lane = tid & 63, nf = tid >> 6;
    const int bid = blockIdx.x;
    const int b = bid / 22, ty = bid - b * 22;
    const int ybase = 6 * ty - 3;
    const int rlane = lane & 15, khalf = lane >> 4;

    // per-lane LDS bases
    int Base2[13];
    #pragma unroll
    for (int f = 0; f < 13; ++f) {
        int m = 16 * f + rlane; m = m < 204 ? m : 203;
        const int my = m / 68, xs = m - my * 68;
        Base2[f] = 2 * my * AROW + (2 * xs + 1) * CHP + khalf * CHP;
    }
    const int Bbase = (nf * 16 + rlane) * BROW + khalf * 8;

    f32x4 acc[13] = {};

    #pragma unroll 1
    for (int c0 = 0; c0 < 256; c0 += 8) {
        __syncthreads();
        // ---- stage A: 16 (r,c4) groups x 139 px, 4 ch/task
        #pragma unroll 1
        for (int i = 0; i < 9; ++i) {
            const int e = tid + 256 * i;
            if (e < 16 * PXS) {
                const int rc = e / PXS, px = e - rc * PXS;
                const int r = rc >> 1, c4 = (rc & 1) << 2;
                const int y = ybase + r, x = px - 4;
                bf16x4 w = {};
                if (((unsigned)y < 128u) && ((unsigned)x < 128u)) {
                    const float* sp = img + (((size_t)(b * 256 + c0 + c4) << 14) + (y << 7) + x);
                    w[0] = (bf16_t)sp[0];
                    w[1] = (bf16_t)sp[16384];
                    w[2] = (bf16_t)sp[32768];
                    w[3] = (bf16_t)sp[49152];
                }
                *(bf16x4*)&As[r * AROW + px * CHP + c4] = w;
            }
        }
        // ---- stage B: 64 outs x 16 taps, 8 ch each (16B)
        #pragma unroll
        for (int i = 0; i < 4; ++i) {
            const int id = tid + 256 * i;
            const int o = id >> 4, tp = id & 15;
            *(bf16x8*)&Bs[o * BROW + tp * 8] =
                *(const bf16x8*)(Wc + ((o << 12) + (tp << 8) + c0));
        }
        __syncthreads();
        // ---- MFMA: 4 ksteps x 13 m-frags
        #pragma unroll
        for (int s = 0; s < 4; ++s) {
            const bf16x8 bf = *(const bf16x8*)&Bs[Bbase + s * 32];
            #pragma unroll
            for (int f = 0; f < 13; ++f) {
                const bf16x4 lo = *(const bf16x4*)&As[Base2[f] + s * AROW];
                const bf16x4 hi = *(const bf16x4*)&As[Base2[f] + s * AROW + 4];
                const bf16x8 af = __builtin_shufflevector(lo, hi, 0, 1, 2, 3, 4, 5, 6, 7);
                acc[f] = __builtin_amdgcn_mfma_f32_16x16x32_bf16(af, bf, acc[f], 0, 0, 0);
            }
        }
    }
    // ---- epilogue: D row=(lane>>4)*4+reg, col=lane&15
    const int rgrp = (lane >> 4) << 2;
    const int o = nf * 16 + rlane;
    #pragma unroll
    for (int f = 0; f < 13; ++f) {
        #pragma unroll
        for (int rg = 0; rg < 4; ++rg) {
            const int m = 16 * f + rgrp + rg;
            if (m < 204) {
                const int my = m / 68, xs = m - my * 68;
                const int yo = 3 * ty + my;
                Oconv[(((size_t)b * YO + yo) * XS + xs) * OC + o] = (bf16_t)acc[f][rg];
            }
        }
    }
}

// ---------------------------------------------------------------------------
// Scatter: local[p][c*64+o] = (Oconv[b][py+2cy][px+2cx][o]+bias[o])*roi[p];
// + folds graph_fill into threads 0..63.
// ---------------------------------------------------------------------------
__global__ __launch_bounds__(256) void scatter_local(
    const bf16_t* __restrict__ Oconv, const float* __restrict__ conv_b,
    const float* __restrict__ roi,
    const int* __restrict__ px, const int* __restrict__ py,
    const float* __restrict__ graph,
    bf16_t* __restrict__ local)
{
    const int p = blockIdx.x;
    const int b = p >> 9, n = p & 511;
    const int t = threadIdx.x;
    const int corner = t >> 6, o = t & 63;
    const int yo = py[p] + ((corner & 1) << 1);
    const int xs = px[p] + (((corner >> 1) & 1) << 1);
    const float v = (float)Oconv[(((size_t)b * YO + yo) * XS + xs) * OC + o] + conv_b[o];
    local[(size_t)p * 320 + t] = (bf16_t)(v * roi[p]);
    if (t < 64)
        local[(size_t)p * 320 + 256 + t] = (bf16_t)graph[((size_t)(b * 64 + t) << 9) + n];
}

// ---------------------------------------------------------------------------
// Generic MFMA GEMM: C[8192][N] = A[8192][K] @ Bt[N][K]^T (+bias, lrelu)
// ---------------------------------------------------------------------------
template<int K, int N, int ACT>
__global__ __launch_bounds__(256) void gemm_bf16(
    const bf16_t* __restrict__ A, const bf16_t* __restrict__ Bt,
    const float* __restrict__ bias, float slope,
    bf16_t* __restrict__ outB, float* __restrict__ outF)
{
    __shared__ bf16_t As[64][72];
    __shared__ bf16_t Bs[64][72];
    const int tid = threadIdx.x;
    const int lane = tid & 63;
    const int wave = tid >> 6;
    const int wm = wave & 1, wn = wave >> 1;
    const int row0 = blockIdx.x * 64;
    const int col0 = blockIdx.y * 64;
    const int sm = tid >> 2;
    const int sq = (tid & 3) << 4;

    f32x4 acc[2][2] = {};
    for (int kt = 0; kt < K; kt += 64) {
        {
            const bf16_t* src = A + (size_t)(row0 + sm) * K + kt + sq;
            *(uint4*)&As[sm][sq]     = *(const uint4*)src;
            *(uint4*)&As[sm][sq + 8] = *(const uint4*)(src + 8);
        }
        {
            const bf16_t* src = Bt + (size_t)(col0 + sm) * K + kt + sq;
            *(uint4*)&Bs[sm][sq]     = *(const uint4*)src;
            *(uint4*)&Bs[sm][sq + 8] = *(const uint4*)(src + 8);
        }
        __syncthreads();
        #pragma unroll
        for (int kk = 0; kk < 64; kk += 32) {
            const int kf = kk + ((lane >> 4) << 3);
            bf16x8 a0 = *(const bf16x8*)&As[wm * 32 + (lane & 15)][kf];
            bf16x8 a1 = *(const bf16x8*)&As[wm * 32 + 16 + (lane & 15)][kf];
            bf16x8 b0 = *(const bf16x8*)&Bs[wn * 32 + (lane & 15)][kf];
            bf16x8 b1 = *(const bf16x8*)&Bs[wn * 32 + 16 + (lane & 15)][kf];
            acc[0][0] = __builtin_amdgcn_mfma_f32_16x16x32_bf16(a0, b0, acc[0][0], 0, 0, 0);
            acc[0][1] = __builtin_amdgcn_mfma_f32_16x16x32_bf16(a0, b1, acc[0][1], 0, 0, 0);
            acc[1][0] = __builtin_amdgcn_mfma_f32_16x16x32_bf16(a1, b0, acc[1][0], 0, 0, 0);
            acc[1][1] = __builtin_amdgcn_mfma_f32_16x16x32_bf16(a1, b1, acc[1][1], 0, 0, 0);
        }
        __syncthreads();
    }
    const int crow = (lane >> 4) << 2;
    const int ccol = lane & 15;
    #pragma unroll
    for (int i = 0; i < 2; ++i) {
        #pragma unroll
        for (int j = 0; j < 2; ++j) {
            const int gcol = col0 + wn * 32 + j * 16 + ccol;
            const float bv = bias ? bias[gcol] : 0.0f;
            #pragma unroll
            for (int rg = 0; rg < 4; ++rg) {
                const int grow = row0 + wm * 32 + i * 16 + crow + rg;
                float v = acc[i][j][rg] + bv;
                if (ACT == 1) v = v >= 0.0f ? v : slope * v;
                if (outB) outB[(size_t)grow * N + gcol] = (bf16_t)v;
                if (outF) outF[(size_t)grow * N + gcol] = v;
            }
        }
    }
}

// ---------------------------------------------------------------------------
// EdgeConv combine
// ---------------------------------------------------------------------------
__global__ __launch_bounds__(256) void edge_combine(
    const float* __restrict__ AB, const int* __restrict__ knn,
    const float* __restrict__ gamma, const float* __restrict__ beta,
    const float* __restrict__ mean,  const float* __restrict__ var,
    bf16_t* __restrict__ outB, float* __restrict__ outT)
{
    const int p = blockIdx.x;
    const int b = p >> 9, n = p & 511;
    const int o = threadIdx.x;
    const float sc = gamma[o] / sqrtf(var[o] + 1e-5f);
    const float sh = beta[o] - mean[o] * sc;
    const float* rowp = AB + (size_t)p * 512;
    const float d = rowp[256 + o] - rowp[o];
    const float* batch = AB + ((size_t)(b << 9)) * 512;
    float m = -3.4e38f;
    #pragma unroll 4
    for (int k = 0; k < 20; ++k) {
        const int q = knn[n * 20 + k];
        const float v = batch[(size_t)q * 512 + o] + d;
        float y = v * sc + sh;
        y = y >= 0.0f ? y : 0.2f * y;
        m = fmaxf(m, y);
    }
    outB[(size_t)p * 256 + o] = (bf16_t)m;
    if (outT) outT[((size_t)(b * 256 + o) << 9) + n] = m;
}

// ---------------------------------------------------------------------------
// Head final layer
// ---------------------------------------------------------------------------
__global__ __launch_bounds__(256) void q3_kernel(
    const bf16_t* __restrict__ Z, const float* __restrict__ w3,
    const float* __restrict__ b3, float* __restrict__ out)
{
    const int p = blockIdx.x * 256 + threadIdx.x;
    const int b = p >> 9, n = p & 511;
    const bf16_t* q = Z + (size_t)p * 64;
    float s0 = b3[0], s1 = b3[1];
    #pragma unroll
    for (int c = 0; c < 64; ++c) {
        const float v = (float)q[c];
        s0 += v * w3[2 * c];
        s1 += v * w3[2 * c + 1];
    }
    out[(size_t)(b * 2 + 0) * 512 + n] = s0;
    out[(size_t)(b * 2 + 1) * 512 + n] = s1;
}

// ---------------------------------------------------------------------------
extern "C" void kernel_launch(void* const* d_in, const int* in_sizes, int n_in,
                              void* d_out, int out_size, void* d_ws, size_t ws_size,
                              hipStream_t stream)
{
    const float* img      = (const float*)d_in[0];
    const float* graph    = (const float*)d_in[1];
    const float* roi      = (const float*)d_in[2];
    const int*   px       = (const int*)d_in[3];
    const int*   py       = (const int*)d_in[4];
    const int*   knn      = (const int*)d_in[5];
    const float* conv_w   = (const float*)d_in[6];
    const float* conv_b   = (const float*)d_in[7];
    const float* pre_w1   = (const float*)d_in[8];
    const float* pre_b1   = (const float*)d_in[9];
    const float* pre_w2   = (const float*)d_in[10];
    const float* pre_b2   = (const float*)d_in[11];
    const float* g1_w     = (const float*)d_in[12];
    const float* g1_gamma = (const float*)d_in[13];
    const float* g1_beta  = (const float*)d_in[14];
    const float* g1_mean  = (const float*)d_in[15];
    const float* g1_var   = (const float*)d_in[16];
    const float* g2_w     = (const float*)d_in[17];
    const float* g2_gamma = (const float*)d_in[18];
    const float* g2_beta  = (const float*)d_in[19];
    const float* g2_mean  = (const float*)d_in[20];
    const float* g2_var   = (const float*)d_in[21];
    const float* q_w1     = (const float*)d_in[22];
    const float* q_b1     = (const float*)d_in[23];
    const float* q_w2     = (const float*)d_in[24];
    const float* q_b2     = (const float*)d_in[25];
    const float* q_w3     = (const float*)d_in[26];
    const float* q_b3     = (const float*)d_in[27];
    float* out = (float*)d_out;

    if (ws_size < WS_NEEDED) return;

    char* ws = (char*)d_ws;
    bf16_t* wt_convp = (bf16_t*)(ws + OFF_WCONVP);
    bf16_t* wt_pre1  = (bf16_t*)(ws + OFF_WPRE1);
    bf16_t* wt_pre2  = (bf16_t*)(ws + OFF_WPRE2);
    bf16_t* wt_ec1   = (bf16_t*)(ws + OFF_WEC1);
    bf16_t* wt_ec2   = (bf16_t*)(ws + OFF_WEC2);
    bf16_t* wt_q1    = (bf16_t*)(ws + OFF_WQ1);
    bf16_t* wt_q2    = (bf16_t*)(ws + OFF_WQ2);
    bf16_t* local    = (bf16_t*)(ws + OFF_LOCAL);
    bf16_t* X        = (bf16_t*)(ws + OFF_X);
    bf16_t* Y        = (bf16_t*)(ws + OFF_Y);
    bf16_t* Z        = (bf16_t*)(ws + OFF_Z);
    float*  AB       = (float*)(ws + OFF_UNION);
    bf16_t* Oconv    = (bf16_t*)(ws + OFF_UNION);   // union w/ AB (used first)

    wprep_kernel<<<(WP_TOTAL + 255) / 256, 256, 0, stream>>>(
        conv_w, pre_w1, pre_w2, g1_w, g2_w, q_w1, q_w2,
        wt_convp, wt_pre1, wt_pre2, wt_ec1, wt_ec2, wt_q1, wt_q2);

    conv_dense<<<16 * 22, 256, 0, stream>>>(img, wt_convp, Oconv);

    scatter_local<<<PTS, 256, 0, stream>>>(
        Oconv, conv_b, roi, px, py, graph, local);

    gemm_bf16<320, 256, 1><<<dim3(PTS / 64, 4), 256, 0, stream>>>(
        local, wt_pre1, pre_b1, 0.01f, X, nullptr);
    gemm_bf16<256, 256, 1><<<dim3(PTS / 64, 4), 256, 0, stream>>>(
        X, wt_pre2, pre_b2, 0.01f, Y, nullptr);

    gemm_bf16<256, 512, 0><<<dim3(PTS / 64, 8), 256, 0, stream>>>(
        Y, wt_ec1, nullptr, 0.0f, nullptr, AB);
    edge_combine<<<PTS, 256, 0, stream>>>(
        AB, knn, g1_gamma, g1_beta, g1_mean, g1_var, X, nullptr);

    gemm_bf16<256, 512, 0><<<dim3(PTS / 64, 8), 256, 0, stream>>>(
        X, wt_ec2, nullptr, 0.0f, nullptr, AB);
    edge_combine<<<PTS, 256, 0, stream>>>(
        AB, knn, g2_gamma, g2_beta, g2_mean, g2_var, Y, out + 16384);

    gemm_bf16<256, 256, 1><<<dim3(PTS / 64, 4), 256, 0, stream>>>(
        Y, wt_q1, q_b1, 0.01f, X, nullptr);
    gemm_bf16<256, 64, 1><<<dim3(PTS / 64, 1), 256, 0, stream>>>(
        X, wt_q2, q_b2, 0.01f, Z, nullptr);
    q3_kernel<<<PTS / 256, 256, 0, stream>>>(Z, q_w3, q_b3, out);
}

// Round 7
// 329.228 us; speedup vs baseline: 1.1703x; 1.1703x over previous
//
#include <hip/hip_runtime.h>

// ---------------------------------------------------------------------------
// Refine_moduleGNN: dense strided conv + pre-MLP + 2x EdgeConv + head (MFMA).
// R3 best = 265us (transpose+gather conv 150us + tail 115us).
// R6 dense conv = 313us: latency-serial (1.4 blocks/CU, unroll-1 staging).
// R7: dense conv v2 -- 1408 blocks (x-halves x ch-halves), load-then-write
//     unrolled staging, f32 partial sums, reduce fused into scatter.
//     Index mapping identical to R6 (correctness-verified).
// ---------------------------------------------------------------------------

typedef __bf16 bf16_t;
typedef bf16_t bf16x4 __attribute__((ext_vector_type(4)));
typedef bf16_t bf16x8 __attribute__((ext_vector_type(8)));
typedef float  f32x4  __attribute__((ext_vector_type(4)));

static constexpr int BATCH = 16;
static constexpr int NPT   = 512;
static constexpr int PTS   = BATCH * NPT;   // 8192

// dense conv output grid: 66 even yo x 68 xslots (66 valid) x 64 ch
static constexpr int YO = 66, XS = 68, OC = 64;
static constexpr size_t PARTSZ = (size_t)BATCH * YO * XS * OC;   // 4.6M f32

// ---- workspace layout (bytes) ----
static constexpr size_t OFF_WCONVP = 0;                                  // [64][16][256]
static constexpr size_t OFF_WPRE1  = OFF_WCONVP + (size_t)64*4096*2;     // [256][320]
static constexpr size_t OFF_WPRE2  = OFF_WPRE1  + (size_t)256*320*2;     // [256][256]
static constexpr size_t OFF_WEC1   = OFF_WPRE2  + (size_t)256*256*2;     // [512][256]
static constexpr size_t OFF_WEC2   = OFF_WEC1   + (size_t)512*256*2;
static constexpr size_t OFF_WQ1    = OFF_WEC2   + (size_t)512*256*2;     // [256][256]
static constexpr size_t OFF_WQ2    = OFF_WQ1    + (size_t)256*256*2;     // [64][256]
static constexpr size_t OFF_LOCAL  = OFF_WQ2    + (size_t)64*256*2;      // [8192][320] bf16
static constexpr size_t OFF_X      = OFF_LOCAL  + (size_t)PTS*320*2;
static constexpr size_t OFF_Y      = OFF_X      + (size_t)PTS*256*2;
static constexpr size_t OFF_Z      = OFF_Y      + (size_t)PTS*256*2;     // [8192][64]
// union: AB f32 (edgeconv) | partials f32 x2 (conv, used before AB)
static constexpr size_t OFF_UNION  = OFF_Z      + (size_t)PTS*64*2;
static constexpr size_t UNION_BYTES = 2 * PARTSZ * 4;                    // 36.8 MB > AB 16 MB
static constexpr size_t WS_NEEDED  = OFF_UNION + UNION_BYTES;            // ~54 MB

// ---------------------------------------------------------------------------
// Weight prep: fp32 -> bf16, transposed layouts.
// ---------------------------------------------------------------------------
static constexpr int WP_CONVP = 64*4096;
static constexpr int WP_PRE1 = 256*320;
static constexpr int WP_PRE2 = 256*256;
static constexpr int WP_EC   = 512*256;
static constexpr int WP_Q1   = 256*256;
static constexpr int WP_Q2   = 64*256;
static constexpr int WP_TOTAL = WP_CONVP + WP_PRE1 + WP_PRE2 + 2*WP_EC + WP_Q1 + WP_Q2;

__global__ __launch_bounds__(256) void wprep_kernel(
    const float* __restrict__ conv_w, const float* __restrict__ pre_w1,
    const float* __restrict__ pre_w2, const float* __restrict__ g1_w,
    const float* __restrict__ g2_w,   const float* __restrict__ q_w1,
    const float* __restrict__ q_w2,
    bf16_t* __restrict__ wt_convp, bf16_t* __restrict__ wt_pre1,
    bf16_t* __restrict__ wt_pre2,  bf16_t* __restrict__ wt_ec1,
    bf16_t* __restrict__ wt_ec2,   bf16_t* __restrict__ wt_q1,
    bf16_t* __restrict__ wt_q2)
{
    int i = blockIdx.x * 256 + threadIdx.x;
    if (i >= WP_TOTAL) return;
    if (i < WP_CONVP) {   // [o][pix][c] <- conv_w[(o*256+c)*16 + pix]
        const int o = i >> 12, pix = (i >> 8) & 15, c = i & 255;
        wt_convp[i] = (bf16_t)conv_w[((o * 256 + c) << 4) + pix]; return; }
    i -= WP_CONVP;
    if (i < WP_PRE1) { int n = i / 320, k = i - n * 320;
        wt_pre1[i] = (bf16_t)pre_w1[k * 256 + n]; return; }
    i -= WP_PRE1;
    if (i < WP_PRE2) { int n = i >> 8, k = i & 255;
        wt_pre2[i] = (bf16_t)pre_w2[k * 256 + n]; return; }
    i -= WP_PRE2;
    if (i < WP_EC) { int n = i >> 8, k = i & 255;
        wt_ec1[i] = (bf16_t)(n < 256 ? g1_w[n * 512 + k] : g1_w[(n - 256) * 512 + 256 + k]);
        return; }
    i -= WP_EC;
    if (i < WP_EC) { int n = i >> 8, k = i & 255;
        wt_ec2[i] = (bf16_t)(n < 256 ? g2_w[n * 512 + k] : g2_w[(n - 256) * 512 + 256 + k]);
        return; }
    i -= WP_EC;
    if (i < WP_Q1) { int n = i >> 8, k = i & 255;
        wt_q1[i] = (bf16_t)q_w1[k * 256 + n]; return; }
    i -= WP_Q1;
    { int n = i >> 8, k = i & 255;
        wt_q2[i] = (bf16_t)q_w2[k * 64 + n]; }
}

// ---------------------------------------------------------------------------
// Dense strided conv v2.
// Block = (b*22+ty, xh, chq): 3 even-yo rows x 34 xs cols x 128 ch (K-half).
// Per 8-ch chunk: stage 8 input rows x 72 px -> LDS bf16; 4 MFMA ksteps x
// 7 m-frags. Partial f32 written to part[chq]. Mapping verified in R6:
//   input y = 2*yo - 3 + s (s=ky), px slot = 2*xsl + 1 + khalf (kx=khalf).
// ---------------------------------------------------------------------------
static constexpr int PXS2 = 72;           // px slots, x = xh*68 - 4 + slot
static constexpr int CHP  = 12;           // ch pad (8 used)
static constexpr int AROW = PXS2 * CHP;   // 864 el
static constexpr int BROW = 152;          // 128 el used + pad
static constexpr int NTASK = 8 * 2 * PXS2;   // 1152 staging tasks/chunk

__global__ __launch_bounds__(256) void conv_dense2(
    const float* __restrict__ img,        // [16][256][128][128]
    const bf16_t* __restrict__ Wc,        // [64][16][256] (o, pix, c)
    float* __restrict__ part)             // [2][16][66][68][64] f32
{
    __shared__ bf16_t As[8 * AROW];       // 13.8 KB
    __shared__ bf16_t Bs[64 * BROW];      // 19.5 KB
    const int tid = threadIdx.x, lane = tid & 63, nf = tid >> 6;
    const int bid = blockIdx.x;
    const int b = bid / 22, ty = bid - b * 22;
    const int xh = blockIdx.y, chq = blockIdx.z;
    const int ybase = 6 * ty - 3;
    const int xoff = xh * 68 - 4;
    const int rlane = lane & 15, khalf = lane >> 4;

    // per-lane LDS A bases (m = output index within block tile)
    int Base2[7];
    #pragma unroll
    for (int f = 0; f < 7; ++f) {
        int m = 16 * f + rlane; m = m < 102 ? m : 101;
        const int my = m / 34, xsl = m - my * 34;
        Base2[f] = 2 * my * AROW + (2 * xsl + 1 + khalf) * CHP;
    }
    const int Bbase = (nf * 16 + rlane) * BROW + khalf * 8;
    const float* base = img + ((size_t)(b * 256 + chq * 128) << 14);
    const bf16_t* wbase = Wc + chq * 128;

    f32x4 acc[7] = {};

    #pragma unroll 1
    for (int c0 = 0; c0 < 128; c0 += 8) {
        __syncthreads();
        // ---- stage A: load-then-write, all 20 loads in flight
        float t0[5], t1[5], t2[5], t3[5];
        int ldso[5]; bool wr[5];
        #pragma unroll
        for (int i = 0; i < 5; ++i) {
            const int e = tid + 256 * i;
            const int rc = e / PXS2, pxs = e - rc * PXS2;
            const int r = rc >> 1, c4 = (rc & 1) << 2;
            const int y = ybase + r, x = xoff + pxs;
            const bool inb = ((unsigned)y < 128u) && ((unsigned)x < 128u);
            wr[i] = e < NTASK;
            ldso[i] = r * AROW + pxs * CHP + c4;
            int off = ((c0 + c4) << 14) + (y << 7) + x;
            if (!(wr[i] && inb)) off = -1;
            t0[i] = t1[i] = t2[i] = t3[i] = 0.0f;
            if (off >= 0) {
                const float* sp = base + off;
                t0[i] = sp[0];     t1[i] = sp[16384];
                t2[i] = sp[32768]; t3[i] = sp[49152];
            }
        }
        #pragma unroll
        for (int i = 0; i < 5; ++i) {
            if (wr[i]) {
                bf16x4 w;
                w[0] = (bf16_t)t0[i]; w[1] = (bf16_t)t1[i];
                w[2] = (bf16_t)t2[i]; w[3] = (bf16_t)t3[i];
                *(bf16x4*)&As[ldso[i]] = w;
            }
        }
        // ---- stage B: 64 o x 16 taps x 8 ch
        #pragma unroll
        for (int i = 0; i < 4; ++i) {
            const int id = tid + 256 * i;
            const int o = id >> 4, tp = id & 15;
            *(bf16x8*)&Bs[o * BROW + tp * 8] =
                *(const bf16x8*)(wbase + (o << 12) + (tp << 8) + c0);
        }
        __syncthreads();
        // ---- MFMA: 4 ksteps (ky=s) x 7 m-frags
        #pragma unroll
        for (int s = 0; s < 4; ++s) {
            const bf16x8 bf = *(const bf16x8*)&Bs[Bbase + s * 32];
            #pragma unroll
            for (int f = 0; f < 7; ++f) {
                const bf16x4 lo = *(const bf16x4*)&As[Base2[f] + s * AROW];
                const bf16x4 hi = *(const bf16x4*)&As[Base2[f] + s * AROW + 4];
                const bf16x8 af = __builtin_shufflevector(lo, hi, 0, 1, 2, 3, 4, 5, 6, 7);
                acc[f] = __builtin_amdgcn_mfma_f32_16x16x32_bf16(af, bf, acc[f], 0, 0, 0);
            }
        }
    }
    // ---- epilogue: D row=(lane>>4)*4+rg, col=lane&15
    const int rgrp = (lane >> 4) << 2;
    const int o = nf * 16 + rlane;
    float* pp = part + (size_t)chq * PARTSZ;
    #pragma unroll
    for (int f = 0; f < 7; ++f) {
        #pragma unroll
        for (int rg = 0; rg < 4; ++rg) {
            const int m = 16 * f + rgrp + rg;
            if (m < 102) {
                const int my = m / 34, xsl = m - my * 34;
                const int yo = 3 * ty + my;
                const int xs = xh * 34 + xsl;
                pp[(((size_t)b * YO + yo) * XS + xs) * OC + o] = acc[f][rg];
            }
        }
    }
}

// ---------------------------------------------------------------------------
// Scatter + partial-reduce: local[p][c*64+o] =
//   (part0[...] + part1[...] + bias[o]) * roi[p]; + graph fold-in.
// ---------------------------------------------------------------------------
__global__ __launch_bounds__(256) void scatter_local2(
    const float* __restrict__ part, const float* __restrict__ conv_b,
    const float* __restrict__ roi,
    const int* __restrict__ px, const int* __restrict__ py,
    const float* __restrict__ graph,
    bf16_t* __restrict__ local)
{
    const int p = blockIdx.x;
    const int b = p >> 9, n = p & 511;
    const int t = threadIdx.x;
    const int corner = t >> 6, o = t & 63;
    const int yo = py[p] + ((corner & 1) << 1);
    const int xs = px[p] + (((corner >> 1) & 1) << 1);
    const size_t idx = (((size_t)b * YO + yo) * XS + xs) * OC + o;
    const float v = part[idx] + part[PARTSZ + idx] + conv_b[o];
    local[(size_t)p * 320 + t] = (bf16_t)(v * roi[p]);
    if (t < 64)
        local[(size_t)p * 320 + 256 + t] = (bf16_t)graph[((size_t)(b * 64 + t) << 9) + n];
}

// ---------------------------------------------------------------------------
// Generic MFMA GEMM: C[8192][N] = A[8192][K] @ Bt[N][K]^T (+bias, lrelu)
// ---------------------------------------------------------------------------
template<int K, int N, int ACT>
__global__ __launch_bounds__(256) void gemm_bf16(
    const bf16_t* __restrict__ A, const bf16_t* __restrict__ Bt,
    const float* __restrict__ bias, float slope,
    bf16_t* __restrict__ outB, float* __restrict__ outF)
{
    __shared__ bf16_t As[64][72];
    __shared__ bf16_t Bs[64][72];
    typedef bf16_t bf16x8l __attribute__((ext_vector_type(8)));
    const int tid = threadIdx.x;
    const int lane = tid & 63;
    const int wave = tid >> 6;
    const int wm = wave & 1, wn = wave >> 1;
    const int row0 = blockIdx.x * 64;
    const int col0 = blockIdx.y * 64;
    const int sm = tid >> 2;
    const int sq = (tid & 3) << 4;

    f32x4 acc[2][2] = {};
    for (int kt = 0; kt < K; kt += 64) {
        {
            const bf16_t* src = A + (size_t)(row0 + sm) * K + kt + sq;
            *(uint4*)&As[sm][sq]     = *(const uint4*)src;
            *(uint4*)&As[sm][sq + 8] = *(const uint4*)(src + 8);
        }
        {
            const bf16_t* src = Bt + (size_t)(col0 + sm) * K + kt + sq;
            *(uint4*)&Bs[sm][sq]     = *(const uint4*)src;
            *(uint4*)&Bs[sm][sq + 8] = *(const uint4*)(src + 8);
        }
        __syncthreads();
        #pragma unroll
        for (int kk = 0; kk < 64; kk += 32) {
            const int kf = kk + ((lane >> 4) << 3);
            bf16x8 a0 = *(const bf16x8*)&As[wm * 32 + (lane & 15)][kf];
            bf16x8 a1 = *(const bf16x8*)&As[wm * 32 + 16 + (lane & 15)][kf];
            bf16x8 b0 = *(const bf16x8*)&Bs[wn * 32 + (lane & 15)][kf];
            bf16x8 b1 = *(const bf16x8*)&Bs[wn * 32 + 16 + (lane & 15)][kf];
            acc[0][0] = __builtin_amdgcn_mfma_f32_16x16x32_bf16(a0, b0, acc[0][0], 0, 0, 0);
            acc[0][1] = __builtin_amdgcn_mfma_f32_16x16x32_bf16(a0, b1, acc[0][1], 0, 0, 0);
            acc[1][0] = __builtin_amdgcn_mfma_f32_16x16x32_bf16(a1, b0, acc[1][0], 0, 0, 0);
            acc[1][1] = __builtin_amdgcn_mfma_f32_16x16x32_bf16(a1, b1, acc[1][1], 0, 0, 0);
        }
        __syncthreads();
    }
    const int crow = (lane >> 4) << 2;
    const int ccol = lane & 15;
    #pragma unroll
    for (int i = 0; i < 2; ++i) {
        #pragma unroll
        for (int j = 0; j < 2; ++j) {
            const int gcol = col0 + wn * 32 + j * 16 + ccol;
            const float bv = bias ? bias[gcol] : 0.0f;
            #pragma unroll
            for (int rg = 0; rg < 4; ++rg) {
                const int grow = row0 + wm * 32 + i * 16 + crow + rg;
                float v = acc[i][j][rg] + bv;
                if (ACT == 1) v = v >= 0.0f ? v : slope * v;
                if (outB) outB[(size_t)grow * N + gcol] = (bf16_t)v;
                if (outF) outF[(size_t)grow * N + gcol] = v;
            }
        }
    }
}

// ---------------------------------------------------------------------------
// EdgeConv combine
// ---------------------------------------------------------------------------
__global__ __launch_bounds__(256) void edge_combine(
    const float* __restrict__ AB, const int* __restrict__ knn,
    const float* __restrict__ gamma, const float* __restrict__ beta,
    const float* __restrict__ mean,  const float* __restrict__ var,
    bf16_t* __restrict__ outB, float* __restrict__ outT)
{
    const int p = blockIdx.x;
    const int b = p >> 9, n = p & 511;
    const int o = threadIdx.x;
    const float sc = gamma[o] / sqrtf(var[o] + 1e-5f);
    const float sh = beta[o] - mean[o] * sc;
    const float* rowp = AB + (size_t)p * 512;
    const float d = rowp[256 + o] - rowp[o];
    const float* batch = AB + ((size_t)(b << 9)) * 512;
    float m = -3.4e38f;
    #pragma unroll 4
    for (int k = 0; k < 20; ++k) {
        const int q = knn[n * 20 + k];
        const float v = batch[(size_t)q * 512 + o] + d;
        float y = v * sc + sh;
        y = y >= 0.0f ? y : 0.2f * y;
        m = fmaxf(m, y);
    }
    outB[(size_t)p * 256 + o] = (bf16_t)m;
    if (outT) outT[((size_t)(b * 256 + o) << 9) + n] = m;
}

// ---------------------------------------------------------------------------
// Head final layer
// ---------------------------------------------------------------------------
__global__ __launch_bounds__(256) void q3_kernel(
    const bf16_t* __restrict__ Z, const float* __restrict__ w3,
    const float* __restrict__ b3, float* __restrict__ out)
{
    const int p = blockIdx.x * 256 + threadIdx.x;
    const int b = p >> 9, n = p & 511;
    const bf16_t* q = Z + (size_t)p * 64;
    float s0 = b3[0], s1 = b3[1];
    #pragma unroll
    for (int c = 0; c < 64; ++c) {
        const float v = (float)q[c];
        s0 += v * w3[2 * c];
        s1 += v * w3[2 * c + 1];
    }
    out[(size_t)(b * 2 + 0) * 512 + n] = s0;
    out[(size_t)(b * 2 + 1) * 512 + n] = s1;
}

// ---------------------------------------------------------------------------
extern "C" void kernel_launch(void* const* d_in, const int* in_sizes, int n_in,
                              void* d_out, int out_size, void* d_ws, size_t ws_size,
                              hipStream_t stream)
{
    const float* img      = (const float*)d_in[0];
    const float* graph    = (const float*)d_in[1];
    const float* roi      = (const float*)d_in[2];
    const int*   px       = (const int*)d_in[3];
    const int*   py       = (const int*)d_in[4];
    const int*   knn      = (const int*)d_in[5];
    const float* conv_w   = (const float*)d_in[6];
    const float* conv_b   = (const float*)d_in[7];
    const float* pre_w1   = (const float*)d_in[8];
    const float* pre_b1   = (const float*)d_in[9];
    const float* pre_w2   = (const float*)d_in[10];
    const float* pre_b2   = (const float*)d_in[11];
    const float* g1_w     = (const float*)d_in[12];
    const float* g1_gamma = (const float*)d_in[13];
    const float* g1_beta  = (const float*)d_in[14];
    const float* g1_mean  = (const float*)d_in[15];
    const float* g1_var   = (const float*)d_in[16];
    const float* g2_w     = (const float*)d_in[17];
    const float* g2_gamma = (const float*)d_in[18];
    const float* g2_beta  = (const float*)d_in[19];
    const float* g2_mean  = (const float*)d_in[20];
    const float* g2_var   = (const float*)d_in[21];
    const float* q_w1     = (const float*)d_in[22];
    const float* q_b1     = (const float*)d_in[23];
    const float* q_w2     = (const float*)d_in[24];
    const float* q_b2     = (const float*)d_in[25];
    const float* q_w3     = (const float*)d_in[26];
    const float* q_b3     = (const float*)d_in[27];
    float* out = (float*)d_out;

    if (ws_size < WS_NEEDED) return;

    char* ws = (char*)d_ws;
    bf16_t* wt_convp = (bf16_t*)(ws + OFF_WCONVP);
    bf16_t* wt_pre1  = (bf16_t*)(ws + OFF_WPRE1);
    bf16_t* wt_pre2  = (bf16_t*)(ws + OFF_WPRE2);
    bf16_t* wt_ec1   = (bf16_t*)(ws + OFF_WEC1);
    bf16_t* wt_ec2   = (bf16_t*)(ws + OFF_WEC2);
    bf16_t* wt_q1    = (bf16_t*)(ws + OFF_WQ1);
    bf16_t* wt_q2    = (bf16_t*)(ws + OFF_WQ2);
    bf16_t* local    = (bf16_t*)(ws + OFF_LOCAL);
    bf16_t* X        = (bf16_t*)(ws + OFF_X);
    bf16_t* Y        = (bf16_t*)(ws + OFF_Y);
    bf16_t* Z        = (bf16_t*)(ws + OFF_Z);
    float*  AB       = (float*)(ws + OFF_UNION);
    float*  part     = (float*)(ws + OFF_UNION);   // union w/ AB (used first)

    wprep_kernel<<<(WP_TOTAL + 255) / 256, 256, 0, stream>>>(
        conv_w, pre_w1, pre_w2, g1_w, g2_w, q_w1, q_w2,
        wt_convp, wt_pre1, wt_pre2, wt_ec1, wt_ec2, wt_q1, wt_q2);

    conv_dense2<<<dim3(16 * 22, 2, 2), 256, 0, stream>>>(img, wt_convp, part);

    scatter_local2<<<PTS, 256, 0, stream>>>(
        part, conv_b, roi, px, py, graph, local);

    gemm_bf16<320, 256, 1><<<dim3(PTS / 64, 4), 256, 0, stream>>>(
        local, wt_pre1, pre_b1, 0.01f, X, nullptr);
    gemm_bf16<256, 256, 1><<<dim3(PTS / 64, 4), 256, 0, stream>>>(
        X, wt_pre2, pre_b2, 0.01f, Y, nullptr);

    gemm_bf16<256, 512, 0><<<dim3(PTS / 64, 8), 256, 0, stream>>>(
        Y, wt_ec1, nullptr, 0.0f, nullptr, AB);
    edge_combine<<<PTS, 256, 0, stream>>>(
        AB, knn, g1_gamma, g1_beta, g1_mean, g1_var, X, nullptr);

    gemm_bf16<256, 512, 0><<<dim3(PTS / 64, 8), 256, 0, stream>>>(
        X, wt_ec2, nullptr, 0.0f, nullptr, AB);
    edge_combine<<<PTS, 256, 0, stream>>>(
        AB, knn, g2_gamma, g2_beta, g2_mean, g2_var, Y, out + 16384);

    gemm_bf16<256, 256, 1><<<dim3(PTS / 64, 4), 256, 0, stream>>>(
        Y, wt_q1, q_b1, 0.01f, X, nullptr);
    gemm_bf16<256, 64, 1><<<dim3(PTS / 64, 1), 256, 0, stream>>>(
        X, wt_q2, q_b2, 0.01f, Z, nullptr);
    q3_kernel<<<PTS / 256, 256, 0, stream>>>(Z, q_w3, q_b3, out);
}